// Round 3
// baseline (334.367 us; speedup 1.0000x reference)
//
#include <hip/hip_runtime.h>

typedef __attribute__((ext_vector_type(8))) __bf16 bf16x8;
typedef __attribute__((ext_vector_type(4))) float f32x4;
typedef __attribute__((ext_vector_type(4))) float f4;
typedef __attribute__((ext_vector_type(4))) unsigned short ushort4_t;

__device__ inline void gload16(const void* g, void* l) {
  __builtin_amdgcn_global_load_lds(
      (const __attribute__((address_space(1))) unsigned int*)g,
      (__attribute__((address_space(3))) unsigned int*)l, 16, 0, 0);
}

// ---------------------------------------------------------------- converts
__global__ void convert_bf16_k(const float* __restrict__ in, __bf16* __restrict__ out, int n8) {
  int i = blockIdx.x * blockDim.x + threadIdx.x;
  int stride = gridDim.x * blockDim.x;
  for (; i < n8; i += stride) {
    f4 a = ((const f4*)in)[2 * (long long)i];
    f4 b = ((const f4*)in)[2 * (long long)i + 1];
    bf16x8 o;
#pragma unroll
    for (int e = 0; e < 4; e++) { o[e] = (__bf16)a[e]; o[e + 4] = (__bf16)b[e]; }
    ((bf16x8*)out)[i] = o;
  }
}

__global__ void pack_bias_k(const float* __restrict__ bq, const float* __restrict__ bk,
                            const float* __restrict__ bv, float* __restrict__ out) {
  int i = blockIdx.x * 256 + threadIdx.x;
  if (i >= 3072) return;
  const float* src = (i < 1024) ? bq : (i < 2048) ? bk : bv;
  out[i] = src[i & 1023];
}

// W[k][n] fp32 -> Wt[n][k] bf16, 4 weights via z
__global__ void transpose_w_k(const float* __restrict__ W0, const float* __restrict__ W1,
                              const float* __restrict__ W2, const float* __restrict__ W3,
                              __bf16* __restrict__ out) {
  int z = blockIdx.z;
  const float* W = (z == 0) ? W0 : (z == 1) ? W1 : (z == 2) ? W2 : W3;
  __bf16* O = out + (long long)z * 1048576;
  __shared__ float tile[32][33];
  int tx = threadIdx.x, ty = threadIdx.y;
  int n0 = blockIdx.x * 32, k0 = blockIdx.y * 32;
#pragma unroll
  for (int i = 0; i < 4; i++)
    tile[ty + i * 8][tx] = W[(long long)(k0 + ty + i * 8) * 1024 + n0 + tx];
  __syncthreads();
#pragma unroll
  for (int i = 0; i < 4; i++)
    O[(long long)(n0 + ty + i * 8) * 1024 + k0 + tx] = (__bf16)tile[tx][ty + i * 8];
}

// ---------------------------------------------------------------- GEMM: 256x256 tile, BK=64, 8-phase
// C[z] = A[z] (M x K row-major) @ Bt[z]^T (Bt = N x K row-major) + bias.
// 8 waves (2M x 4N), per-wave 128x64 output, acc[8][4] f32x4.
// LDS 160 KiB: A TRIPLE-buffered (3 x 32 KiB) + B double-buffered (2 x 32 KiB),
// XOR-swizzled (row&7)<<4. A(kk+2) issued during tile kk -> ~8 phases (~1.5 kcy)
// of slack, covering HBM-miss latency (~900 cy); B(kk+2) overwrites-behind the
// buffer being read (its ds_reads finish by phase 2). ENDPB waits vmcnt(8):
// 8 loads issue per tile; tile kk's wait drains A/B(kk+1), leaves A/B(kk+2).
// OUT: 0 = bf16 C, 1 = f32 C,
//      2 = fused QKV z-routing: z<2 -> scalar bf16 C (ldc 1024, z*sCz; z==0
//          scaled); z==2 -> V LDS-transposed, coalesced into vt_out[b][d][t].
// SWZ: 0 = generic bijective XCD swizzle (nwg%8==0) - B L2-resident, A streamed
//      2 = packed causal triangle: XCD q = batch q, tri index -> (br,bc), bc<=br
//      3 = batch-local: XCD q = batch q (PV: Vt slice 4MiB = L2-resident)

#define LOADA(BASE, MIB)                                                       \
  _Pragma("unroll") for (int mi = 0; mi < 4; mi++)                             \
      _Pragma("unroll") for (int kh = 0; kh < 2; kh++) {                       \
    int row = ((MIB) + mi) * 16 + ln15;                                        \
    int pb = (row * 128 + (kh * 32 + kq * 8) * 2) ^ ((row & 7) << 4);          \
    a[mi][kh] = *(const bf16x8*)((BASE) + pb);                                 \
  }

#define LOADB(BASE, NIB)                                                       \
  _Pragma("unroll") for (int ni = 0; ni < 2; ni++)                             \
      _Pragma("unroll") for (int kh = 0; kh < 2; kh++) {                       \
    int row = brow0 + ((NIB) + ni) * 16 + ln15;                                \
    int pb = (row * 128 + (kh * 32 + kq * 8) * 2) ^ ((row & 7) << 4);          \
    b[(NIB) + ni][kh] = *(const bf16x8*)((BASE) + pb);                         \
  }

#define MFMAQ(MI0, NI0)                                                        \
  _Pragma("unroll") for (int mi = 0; mi < 4; mi++)                             \
      _Pragma("unroll") for (int ni = 0; ni < 2; ni++)                         \
          _Pragma("unroll") for (int kh = 0; kh < 2; kh++)                     \
              acc[(MI0) + mi][(NI0) + ni] =                                    \
      __builtin_amdgcn_mfma_f32_16x16x32_bf16(a[mi][kh], b[(NI0) + ni][kh],    \
                                              acc[(MI0) + mi][(NI0) + ni], 0, 0, 0);

#define FENCE asm volatile("" ::: "memory")

#define BARW                                           \
  FENCE;                                               \
  __builtin_amdgcn_s_barrier();                        \
  FENCE;                                               \
  __builtin_amdgcn_s_setprio(1);

#define ENDP                                           \
  __builtin_amdgcn_s_setprio(0);                       \
  FENCE;                                               \
  __builtin_amdgcn_s_barrier();                        \
  FENCE;

#define ENDPB                                          \
  __builtin_amdgcn_s_setprio(0);                       \
  asm volatile("s_waitcnt vmcnt(8)" ::: "memory");     \
  __builtin_amdgcn_s_barrier();                        \
  FENCE;

template <int OUT, int SWZ>
__global__ __launch_bounds__(512, 2) void gemm8(
    const __bf16* __restrict__ A0, int lda, long long sAz,
    const __bf16* __restrict__ B0, int ldb, long long sBz,
    void* __restrict__ C0v, int ldc, long long sCz,
    const float* __restrict__ bias0, int sBiasZ,
    float scale_z0, int k_tiles_base, int k_tiles_per_br,
    __bf16* __restrict__ vt_out) {
  int br, bc, z;
  {
    const int lin = (blockIdx.z * gridDim.y + blockIdx.y) * gridDim.x + blockIdx.x;
    if (SWZ == 2) {
      // packed lower triangle, one batch per XCD; c in [0,36) -> (br,bc) bc<=br
      const int q = lin & 7, c = lin >> 3;
      z = q;
      int b0 = (int)((sqrtf((float)(8 * c + 1)) - 1.0f) * 0.5f);
      int c0 = c - ((b0 * (b0 + 1)) >> 1);
      if (c0 < 0) { b0--; c0 = c - ((b0 * (b0 + 1)) >> 1); }
      if (c0 > b0) { b0++; c0 = c - ((b0 * (b0 + 1)) >> 1); }
      br = b0;
      bc = c0;
    } else if (SWZ == 3) {
      // batch-local: XCD q = batch q; c -> (br fast, bc)
      const int q = lin & 7, c = lin >> 3;
      z = q;
      br = c & 7;
      bc = c >> 3;
    } else {
      const int nbx = gridDim.x, nby = gridDim.y;
      const int nwg = nbx * nby * gridDim.z;
      const int cpx = nwg >> 3;
      const int swz = (lin & 7) * cpx + (lin >> 3);
      br = swz % nbx;
      const int tmp = swz / nbx;
      bc = tmp % nby;
      z = tmp / nby;
    }
  }
  const int kt = k_tiles_base + k_tiles_per_br * br;  // >= 2

  // 160 KiB LDS: A bufs at 0,16384,32768 (elems); B bufs at 49152,65536
  __shared__ __align__(16) __bf16 lds[81920];

  const int t = threadIdx.x, w = t >> 6, lane = t & 63;
  const int wm = w >> 2, wn = w & 3;
  const int ln15 = lane & 15, kq = lane >> 4;
  const int bh = wn >> 1, brow0 = (wn & 1) * 64;

  const __bf16* A = A0 + (long long)z * sAz + (long long)br * 256 * lda;
  const __bf16* B = B0 + (long long)z * sBz + (long long)bc * 256 * ldb;

  // pre-swizzled staging source coords (physical->logical, involution)
  int r0s[2], c0s[2];
#pragma unroll
  for (int i = 0; i < 2; i++) {
    int o = i * 8192 + t * 16;
    int lo = o ^ (((o >> 7) & 7) << 4);
    r0s[i] = lo >> 7;
    c0s[i] = (lo & 127) >> 1;
  }
  // hoisted per-thread source pointers (k-tile adds kc*64 only)
  const __bf16 *sA0[2], *sA1[2], *sB0[2], *sB1[2];
#pragma unroll
  for (int i = 0; i < 2; i++) {
    sA0[i] = A + (long long)r0s[i] * lda + c0s[i];
    sA1[i] = A + (long long)(r0s[i] + 128) * lda + c0s[i];
    sB0[i] = B + (long long)r0s[i] * ldb + c0s[i];
    sB1[i] = B + (long long)(r0s[i] + 128) * ldb + c0s[i];
  }

  auto stg = [&](const __bf16* const* src, __bf16* lbase, int g) {
    int kc = g < kt ? g : kt - 1;
#pragma unroll
    for (int i = 0; i < 2; i++)
      gload16(src[i] + kc * 64, lbase + i * 4096 + w * 512);
  };

  f32x4 acc[8][4] = {};
  bf16x8 a[4][2], b[4][2];

  // prologue: A(0),B(0),A(1),B(1); wait oldest 8 -> A(0),B(0) resident
  stg(sA0, lds, 0);
  stg(sA1, lds + 8192, 0);
  stg(sB0, lds + 49152, 0);
  stg(sB1, lds + 49152 + 8192, 0);
  stg(sA0, lds + 16384, 1);
  stg(sA1, lds + 16384 + 8192, 1);
  stg(sB0, lds + 65536, 1);
  stg(sB1, lds + 65536 + 8192, 1);
  asm volatile("s_waitcnt vmcnt(8)" ::: "memory");
  __builtin_amdgcn_s_barrier();
  FENCE;

  int ap = 0;   // A buffer index of tile kk (mod 3)
  int ad = 2;   // A buffer index of tile kk+2 (= (ap+2)%3)
  for (int kk = 0; kk < kt; kk++) {
    __bf16* Ab = lds + ap * 16384;
    __bf16* Bb = lds + 49152 + (kk & 1) * 16384;
    __bf16* Ad = lds + ad * 16384;  // dest for A(kk+2)
    __bf16* Bd = Bb;                // B(kk+2) overwrites-behind
    const char* Aw = (const char*)(Ab + wm * 8192);
    const char* Bw = (const char*)(Bb + bh * 8192);
    // phase 1
    LOADA(Aw, 0) LOADB(Bw, 0)
    stg(sA0, Ad, kk + 2);
    BARW MFMAQ(0, 0) ENDP
    // phase 2
    LOADB(Bw, 2)
    stg(sA1, Ad + 8192, kk + 2);
    BARW MFMAQ(0, 2) ENDP
    // phase 3 (B ds_reads all done by end of phase 2 -> safe to overwrite)
    LOADA(Aw, 4)
    stg(sB0, Bd, kk + 2);
    BARW MFMAQ(4, 2) ENDP
    // phase 4
    stg(sB1, Bd + 8192, kk + 2);
    BARW MFMAQ(4, 0) ENDPB
    ap = (ap == 2) ? 0 : ap + 1;
    ad = (ad == 2) ? 0 : ad + 1;
  }

  // ---- epilogue ----
  if (OUT == 2 && z == 2) {
    // V: stage 256x256 tile into LDS as [d][t] (XOR-swizzled), then coalesced
    // 16B row stores into vt_out[b][d][t]. __syncthreads drains in-flight
    // clamped prefetches (vmcnt(0)) before LDS reuse.
    __syncthreads();
    char* lb = (char*)lds;
    const int dl0 = wn * 64 + ln15;
    const int tl0 = wm * 128 + kq * 4;
#pragma unroll
    for (int mi = 0; mi < 8; mi++) {
#pragma unroll
      for (int ni = 0; ni < 4; ni++) {
        const int d = dl0 + ni * 16;
        const int tl = tl0 + mi * 16;
        const float bb = bias0[2048 + bc * 256 + d];
        ushort4_t p;
#pragma unroll
        for (int j = 0; j < 4; j++) {
          union { __bf16 h; unsigned short u; } cv;
          cv.h = (__bf16)(acc[mi][ni][j] + bb);
          p[j] = cv.u;
        }
        int byte = d * 512 + tl * 2;
        byte ^= (d & 7) << 4;
        *(ushort4_t*)(lb + byte) = p;
      }
    }
    __syncthreads();
    const int bz = br >> 3;
    __bf16* vbase = vt_out + (long long)bz * 2097152 +
                    (long long)(bc * 256) * 2048 + (br & 7) * 256;
#pragma unroll
    for (int it = 0; it < 16; it++) {
      int idx = it * 512 + t;
      int d = idx >> 5, tc = idx & 31;
      int byte = d * 512 + tc * 16;
      byte ^= (d & 7) << 4;
      bf16x8 vv = *(const bf16x8*)(lb + byte);
      *(bf16x8*)(vbase + (long long)d * 2048 + tc * 8) = vv;
    }
  } else {
    const int row0 = br * 256 + wm * 128 + kq * 4;
    const int col0 = bc * 256 + wn * 64 + ln15;
    const float scale = (z == 0) ? scale_z0 : 1.0f;
    const float* bias = bias0 ? (bias0 + (long long)z * sBiasZ) : nullptr;
#pragma unroll
    for (int mi = 0; mi < 8; mi++) {
#pragma unroll
      for (int ni = 0; ni < 4; ni++) {
        const int rr = row0 + mi * 16;
        const int cc = col0 + ni * 16;
        const float bb = bias ? bias[cc] : 0.0f;
#pragma unroll
        for (int j = 0; j < 4; j++) {
          float v = (acc[mi][ni][j] + bb) * scale;
          long long off = (long long)z * sCz + (long long)(rr + j) * ldc + cc;
          if (OUT == 1)
            ((float*)C0v)[off] = v;
          else
            ((__bf16*)C0v)[off] = (__bf16)v;
        }
      }
    }
  }
}

// ---------------------------------------------------------------- softmax (causal, in-place on S bf16)
__global__ __launch_bounds__(256) void softmax_rows(__bf16* __restrict__ S) {
  const int row = blockIdx.x;  // 0..16383 = b*2048 + i
  const int i = row & 2047;
  __bf16* s = S + (long long)row * 2048;
  const int Lpad = (i + 256) & ~255;  // round_up(i+1, 256): PV reads this far
  const int t = threadIdx.x;
  const int j0 = t * 8;
  const int wid = t >> 6, lane = t & 63;
  const bool active = j0 < Lpad;

  float v[8];
  float mymax = -3.0e38f;
  if (active) {
    bf16x8 x = *(const bf16x8*)(s + j0);
#pragma unroll
    for (int e = 0; e < 8; e++) {
      float f = (float)x[e];
      v[e] = ((j0 + e) <= i) ? f : -3.0e38f;
      mymax = fmaxf(mymax, v[e]);
    }
  }
  float mw = mymax;
#pragma unroll
  for (int o = 32; o >= 1; o >>= 1) mw = fmaxf(mw, __shfl_xor(mw, o));
  __shared__ float redm[4];
  __shared__ float reds[4];
  if (lane == 0) redm[wid] = mw;
  __syncthreads();
  const float m = fmaxf(fmaxf(redm[0], redm[1]), fmaxf(redm[2], redm[3]));

  float e8[8];
  float mysum = 0.0f;
  if (active) {
#pragma unroll
    for (int e = 0; e < 8; e++) {
      float ev = ((j0 + e) <= i) ? __expf(v[e] - m) : 0.0f;
      e8[e] = ev;
      mysum += ev;
    }
  } else {
#pragma unroll
    for (int e = 0; e < 8; e++) e8[e] = 0.0f;
  }
  float sw = mysum;
#pragma unroll
  for (int o = 32; o >= 1; o >>= 1) sw += __shfl_xor(sw, o);
  if (lane == 0) reds[wid] = sw;
  __syncthreads();
  const float l = reds[0] + reds[1] + reds[2] + reds[3];
  const float rl = 1.0f / l;
  if (active) {
    bf16x8 o;
#pragma unroll
    for (int e = 0; e < 8; e++) o[e] = (__bf16)(e8[e] * rl);
    *(bf16x8*)(s + j0) = o;
  }
}

// ---------------------------------------------------------------- launch
extern "C" void kernel_launch(void* const* d_in, const int* in_sizes, int n_in,
                              void* d_out, int out_size, void* d_ws, size_t ws_size,
                              hipStream_t stream) {
  const float* y  = (const float*)d_in[0];
  const float* Wq = (const float*)d_in[1];
  const float* bq = (const float*)d_in[2];
  const float* Wk = (const float*)d_in[3];
  const float* bk = (const float*)d_in[4];
  const float* Wv = (const float*)d_in[5];
  const float* bv = (const float*)d_in[6];
  const float* Wo = (const float*)d_in[7];
  const float* bo = (const float*)d_in[8];

  char* ws = (char*)d_ws;
  __bf16* Xb   = (__bf16*)(ws + 0);            // 16384x1024 bf16 X   (32 MiB) [ctx after PV]
  __bf16* Wt   = (__bf16*)(ws + 33554432);     // 4 x [1024][1024] bf16 W^T (8 MiB)
  float*  bqkv = (float*)(ws + 41943040);      // 3x1024 fp32
  __bf16* Qb   = (__bf16*)(ws + 41955328);     // 8x2048x1024 Q       (32 MiB)
  __bf16* Kb   = (__bf16*)(ws + 75509760);     // 8x2048x1024 K       (32 MiB, = Qb + 16777216 elems)
  __bf16* Vt   = (__bf16*)(ws + 109064192);    // 8 x [1024][2048] V^T (32 MiB)
  __bf16* Sb   = (__bf16*)(ws + 142618624);    // 8x2048x2048 S/P (ends at 209,727,488)
  __bf16* ctx  = (__bf16*)(ws + 0);            // PV output reuses Xb region

  if (ws_size < 209727488u) return;

  convert_bf16_k<<<2048, 256, 0, stream>>>(y, Xb, 2097152);
  pack_bias_k<<<12, 256, 0, stream>>>(bq, bk, bv, bqkv);
  transpose_w_k<<<dim3(32, 32, 4), dim3(32, 8), 0, stream>>>(Wq, Wk, Wv, Wo, Wt);

  // Fused QKV projection: single launch, z-split (z0->Qb scaled, z1->Kb,
  // z2->Vt via LDS transpose). Generic swizzle: B (2 MiB/z) L2-resident,
  // A streamed + prefetched 2 tiles deep.
  gemm8<2, 0><<<dim3(64, 4, 3), 512, 0, stream>>>(
      Xb, 1024, 0LL, Wt, 1024, 1048576LL,
      Qb, 1024, 16777216LL, bqkv, 1024, 0.03125f, 16, 0, Vt);

  // S = Q @ K^T per batch: packed lower-triangle launch (36 tiles x 8 batches)
  gemm8<0, 2><<<dim3(36, 1, 8), 512, 0, stream>>>(
      Qb, 1024, 2097152LL, Kb, 1024, 2097152LL,
      Sb, 2048, 4194304LL, nullptr, 0, 1.0f, 16, 0, nullptr);

  // causal softmax in place (zero-pads to 256-block edge)
  softmax_rows<<<16384, 256, 0, stream>>>(Sb);

  // ctx = P @ V : kt = 4*(br+1) causal truncation; batch-local swizzle
  // (Vt slice 4 MiB = L2-resident per XCD); ctx into Xb region
  gemm8<0, 3><<<dim3(8, 4, 8), 512, 0, stream>>>(
      Sb, 2048, 4194304LL, Vt, 2048, 2097152LL,
      ctx, 1024, 2097152LL, nullptr, 0, 1.0f, 4, 4, nullptr);

  // out = ctx @ Wo + bo (fp32 epilogue to d_out)
  gemm8<1, 0><<<dim3(64, 4, 1), 512, 0, stream>>>(
      ctx, 1024, 0LL, Wt + 3 * 1048576, 1024, 0LL,
      d_out, 1024, 0LL, bo, 0, 1.0f, 16, 0, nullptr);
}

// Round 4
// 317.139 us; speedup vs baseline: 1.0543x; 1.0543x over previous
//
#include <hip/hip_runtime.h>

typedef __attribute__((ext_vector_type(8))) __bf16 bf16x8;
typedef __attribute__((ext_vector_type(4))) float f32x4;
typedef __attribute__((ext_vector_type(4))) float f4;
typedef __attribute__((ext_vector_type(4))) unsigned short ushort4_t;

__device__ inline void gload16(const void* g, void* l) {
  __builtin_amdgcn_global_load_lds(
      (const __attribute__((address_space(1))) unsigned int*)g,
      (__attribute__((address_space(3))) unsigned int*)l, 16, 0, 0);
}

// ---------------------------------------------------------------- converts
__global__ void convert_bf16_k(const float* __restrict__ in, __bf16* __restrict__ out, int n8) {
  int i = blockIdx.x * blockDim.x + threadIdx.x;
  int stride = gridDim.x * blockDim.x;
  for (; i < n8; i += stride) {
    f4 a = ((const f4*)in)[2 * (long long)i];
    f4 b = ((const f4*)in)[2 * (long long)i + 1];
    bf16x8 o;
#pragma unroll
    for (int e = 0; e < 4; e++) { o[e] = (__bf16)a[e]; o[e + 4] = (__bf16)b[e]; }
    ((bf16x8*)out)[i] = o;
  }
}

__global__ void pack_bias_k(const float* __restrict__ bq, const float* __restrict__ bk,
                            const float* __restrict__ bv, float* __restrict__ out) {
  int i = blockIdx.x * 256 + threadIdx.x;
  if (i >= 3072) return;
  const float* src = (i < 1024) ? bq : (i < 2048) ? bk : bv;
  out[i] = src[i & 1023];
}

// W[k][n] fp32 -> Wt[n][k] bf16, 4 weights via z
__global__ void transpose_w_k(const float* __restrict__ W0, const float* __restrict__ W1,
                              const float* __restrict__ W2, const float* __restrict__ W3,
                              __bf16* __restrict__ out) {
  int z = blockIdx.z;
  const float* W = (z == 0) ? W0 : (z == 1) ? W1 : (z == 2) ? W2 : W3;
  __bf16* O = out + (long long)z * 1048576;
  __shared__ float tile[32][33];
  int tx = threadIdx.x, ty = threadIdx.y;
  int n0 = blockIdx.x * 32, k0 = blockIdx.y * 32;
#pragma unroll
  for (int i = 0; i < 4; i++)
    tile[ty + i * 8][tx] = W[(long long)(k0 + ty + i * 8) * 1024 + n0 + tx];
  __syncthreads();
#pragma unroll
  for (int i = 0; i < 4; i++)
    O[(long long)(n0 + ty + i * 8) * 1024 + k0 + tx] = (__bf16)tile[tx][ty + i * 8];
}

// ---------------------------------------------------------------- GEMM: 256x256 tile, BK=64, 8-phase
// C[z] = A[z] (M x K row-major) @ Bt[z]^T (Bt = N x K row-major) + bias.
// 8 waves (2M x 4N), per-wave 128x64 output, acc[8][4] f32x4.
// LDS 160 KiB: A TRIPLE-buffered (3 x 32 KiB) + B double-buffered (2 x 32 KiB),
// XOR-swizzled (row&7)<<4. A(kk+2) issued during tile kk; B(kk+2)
// overwrites-behind. ENDPB waits vmcnt(8) (drains tile kk+1's 8 loads, leaves
// kk+2's 8 in flight).
// OUT: 0 = bf16 C, 1 = f32 C,
//      2 = fused QKV z-routing: z<2 -> scalar bf16 C (ldc 1024, z*sCz; z==0
//          scaled); z==2 -> V LDS-transposed, coalesced into vt_out[b][d][t].
// SWZ: 0 = generic bijective XCD swizzle (nwg%8==0)
//      1 = A-stripe: XCD q owns br in [8q,8q+8), br fastest, then z, then bc.
//          Concurrent per-XCD window = A-stripe 4 MiB (L2-resident, reused by
//          all (bc,z)) + <=3 B panels ~1.5 MiB. Requires gridDim.x == 64.
//      2 = packed causal triangle: XCD q = batch q, tri index -> (br,bc), bc<=br
//      3 = batch-local: XCD q = batch q (PV: Vt slice 4MiB = L2-resident)

#define LOADA(BASE, MIB)                                                       \
  _Pragma("unroll") for (int mi = 0; mi < 4; mi++)                             \
      _Pragma("unroll") for (int kh = 0; kh < 2; kh++) {                       \
    int row = ((MIB) + mi) * 16 + ln15;                                        \
    int pb = (row * 128 + (kh * 32 + kq * 8) * 2) ^ ((row & 7) << 4);          \
    a[mi][kh] = *(const bf16x8*)((BASE) + pb);                                 \
  }

#define LOADB(BASE, NIB)                                                       \
  _Pragma("unroll") for (int ni = 0; ni < 2; ni++)                             \
      _Pragma("unroll") for (int kh = 0; kh < 2; kh++) {                       \
    int row = brow0 + ((NIB) + ni) * 16 + ln15;                                \
    int pb = (row * 128 + (kh * 32 + kq * 8) * 2) ^ ((row & 7) << 4);          \
    b[(NIB) + ni][kh] = *(const bf16x8*)((BASE) + pb);                         \
  }

#define MFMAQ(MI0, NI0)                                                        \
  _Pragma("unroll") for (int mi = 0; mi < 4; mi++)                             \
      _Pragma("unroll") for (int ni = 0; ni < 2; ni++)                         \
          _Pragma("unroll") for (int kh = 0; kh < 2; kh++)                     \
              acc[(MI0) + mi][(NI0) + ni] =                                    \
      __builtin_amdgcn_mfma_f32_16x16x32_bf16(a[mi][kh], b[(NI0) + ni][kh],    \
                                              acc[(MI0) + mi][(NI0) + ni], 0, 0, 0);

#define FENCE asm volatile("" ::: "memory")

#define BARW                                           \
  FENCE;                                               \
  __builtin_amdgcn_s_barrier();                        \
  FENCE;                                               \
  __builtin_amdgcn_s_setprio(1);

#define ENDP                                           \
  __builtin_amdgcn_s_setprio(0);                       \
  FENCE;                                               \
  __builtin_amdgcn_s_barrier();                        \
  FENCE;

#define ENDPB                                          \
  __builtin_amdgcn_s_setprio(0);                       \
  asm volatile("s_waitcnt vmcnt(8)" ::: "memory");     \
  __builtin_amdgcn_s_barrier();                        \
  FENCE;

template <int OUT, int SWZ>
__global__ __launch_bounds__(512, 2) void gemm8(
    const __bf16* __restrict__ A0, int lda, long long sAz,
    const __bf16* __restrict__ B0, int ldb, long long sBz,
    void* __restrict__ C0v, int ldc, long long sCz,
    const float* __restrict__ bias0, int sBiasZ,
    float scale_z0, int k_tiles_base, int k_tiles_per_br,
    __bf16* __restrict__ vt_out) {
  int br, bc, z;
  {
    const int lin = (blockIdx.z * gridDim.y + blockIdx.y) * gridDim.x + blockIdx.x;
    if (SWZ == 1) {
      // A-stripe: XCD q -> br in [8q,8q+8), br fastest; then z; then bc.
      const int q = lin & 7, c = lin >> 3;
      br = q * 8 + (c & 7);
      const int rest = c >> 3;
      const int nz = gridDim.z;
      z = rest % nz;
      bc = rest / nz;
    } else if (SWZ == 2) {
      // packed lower triangle, one batch per XCD; c in [0,36) -> (br,bc) bc<=br
      const int q = lin & 7, c = lin >> 3;
      z = q;
      int b0 = (int)((sqrtf((float)(8 * c + 1)) - 1.0f) * 0.5f);
      int c0 = c - ((b0 * (b0 + 1)) >> 1);
      if (c0 < 0) { b0--; c0 = c - ((b0 * (b0 + 1)) >> 1); }
      if (c0 > b0) { b0++; c0 = c - ((b0 * (b0 + 1)) >> 1); }
      br = b0;
      bc = c0;
    } else if (SWZ == 3) {
      // batch-local: XCD q = batch q; c -> (br fast, bc)
      const int q = lin & 7, c = lin >> 3;
      z = q;
      br = c & 7;
      bc = c >> 3;
    } else {
      const int nbx = gridDim.x, nby = gridDim.y;
      const int nwg = nbx * nby * gridDim.z;
      const int cpx = nwg >> 3;
      const int swz = (lin & 7) * cpx + (lin >> 3);
      br = swz % nbx;
      const int tmp = swz / nbx;
      bc = tmp % nby;
      z = tmp / nby;
    }
  }
  const int kt = k_tiles_base + k_tiles_per_br * br;  // >= 2

  // 160 KiB LDS: A bufs at 0,16384,32768 (elems); B bufs at 49152,65536
  __shared__ __align__(16) __bf16 lds[81920];

  const int t = threadIdx.x, w = t >> 6, lane = t & 63;
  const int wm = w >> 2, wn = w & 3;
  const int ln15 = lane & 15, kq = lane >> 4;
  const int bh = wn >> 1, brow0 = (wn & 1) * 64;

  const __bf16* A = A0 + (long long)z * sAz + (long long)br * 256 * lda;
  const __bf16* B = B0 + (long long)z * sBz + (long long)bc * 256 * ldb;

  // pre-swizzled staging source coords (physical->logical, involution)
  int r0s[2], c0s[2];
#pragma unroll
  for (int i = 0; i < 2; i++) {
    int o = i * 8192 + t * 16;
    int lo = o ^ (((o >> 7) & 7) << 4);
    r0s[i] = lo >> 7;
    c0s[i] = (lo & 127) >> 1;
  }
  // hoisted per-thread source pointers (k-tile adds kc*64 only)
  const __bf16 *sA0[2], *sA1[2], *sB0[2], *sB1[2];
#pragma unroll
  for (int i = 0; i < 2; i++) {
    sA0[i] = A + (long long)r0s[i] * lda + c0s[i];
    sA1[i] = A + (long long)(r0s[i] + 128) * lda + c0s[i];
    sB0[i] = B + (long long)r0s[i] * ldb + c0s[i];
    sB1[i] = B + (long long)(r0s[i] + 128) * ldb + c0s[i];
  }

  auto stg = [&](const __bf16* const* src, __bf16* lbase, int g) {
    int kc = g < kt ? g : kt - 1;
#pragma unroll
    for (int i = 0; i < 2; i++)
      gload16(src[i] + kc * 64, lbase + i * 4096 + w * 512);
  };

  f32x4 acc[8][4] = {};
  bf16x8 a[4][2], b[4][2];

  // prologue: A(0),B(0),A(1),B(1); wait oldest 8 -> A(0),B(0) resident
  stg(sA0, lds, 0);
  stg(sA1, lds + 8192, 0);
  stg(sB0, lds + 49152, 0);
  stg(sB1, lds + 49152 + 8192, 0);
  stg(sA0, lds + 16384, 1);
  stg(sA1, lds + 16384 + 8192, 1);
  stg(sB0, lds + 65536, 1);
  stg(sB1, lds + 65536 + 8192, 1);
  asm volatile("s_waitcnt vmcnt(8)" ::: "memory");
  __builtin_amdgcn_s_barrier();
  FENCE;

  int ap = 0;   // A buffer index of tile kk (mod 3)
  int ad = 2;   // A buffer index of tile kk+2 (= (ap+2)%3)
  for (int kk = 0; kk < kt; kk++) {
    __bf16* Ab = lds + ap * 16384;
    __bf16* Bb = lds + 49152 + (kk & 1) * 16384;
    __bf16* Ad = lds + ad * 16384;  // dest for A(kk+2)
    __bf16* Bd = Bb;                // B(kk+2) overwrites-behind
    const char* Aw = (const char*)(Ab + wm * 8192);
    const char* Bw = (const char*)(Bb + bh * 8192);
    // phase 1
    LOADA(Aw, 0) LOADB(Bw, 0)
    stg(sA0, Ad, kk + 2);
    BARW MFMAQ(0, 0) ENDP
    // phase 2
    LOADB(Bw, 2)
    stg(sA1, Ad + 8192, kk + 2);
    BARW MFMAQ(0, 2) ENDP
    // phase 3 (B ds_reads all done by end of phase 2 -> safe to overwrite)
    LOADA(Aw, 4)
    stg(sB0, Bd, kk + 2);
    BARW MFMAQ(4, 2) ENDP
    // phase 4
    stg(sB1, Bd + 8192, kk + 2);
    BARW MFMAQ(4, 0) ENDPB
    ap = (ap == 2) ? 0 : ap + 1;
    ad = (ad == 2) ? 0 : ad + 1;
  }

  // ---- epilogue ----
  if (OUT == 2 && z == 2) {
    // V: stage 256x256 tile into LDS as [d][t] (XOR-swizzled), then coalesced
    // 16B row stores into vt_out[b][d][t]. __syncthreads drains in-flight
    // clamped prefetches (vmcnt(0)) before LDS reuse.
    __syncthreads();
    char* lb = (char*)lds;
    const int dl0 = wn * 64 + ln15;
    const int tl0 = wm * 128 + kq * 4;
#pragma unroll
    for (int mi = 0; mi < 8; mi++) {
#pragma unroll
      for (int ni = 0; ni < 4; ni++) {
        const int d = dl0 + ni * 16;
        const int tl = tl0 + mi * 16;
        const float bb = bias0[2048 + bc * 256 + d];
        ushort4_t p;
#pragma unroll
        for (int j = 0; j < 4; j++) {
          union { __bf16 h; unsigned short u; } cv;
          cv.h = (__bf16)(acc[mi][ni][j] + bb);
          p[j] = cv.u;
        }
        int byte = d * 512 + tl * 2;
        byte ^= (d & 7) << 4;
        *(ushort4_t*)(lb + byte) = p;
      }
    }
    __syncthreads();
    const int bz = br >> 3;
    __bf16* vbase = vt_out + (long long)bz * 2097152 +
                    (long long)(bc * 256) * 2048 + (br & 7) * 256;
#pragma unroll
    for (int it = 0; it < 16; it++) {
      int idx = it * 512 + t;
      int d = idx >> 5, tc = idx & 31;
      int byte = d * 512 + tc * 16;
      byte ^= (d & 7) << 4;
      bf16x8 vv = *(const bf16x8*)(lb + byte);
      *(bf16x8*)(vbase + (long long)d * 2048 + tc * 8) = vv;
    }
  } else {
    const int row0 = br * 256 + wm * 128 + kq * 4;
    const int col0 = bc * 256 + wn * 64 + ln15;
    const float scale = (z == 0) ? scale_z0 : 1.0f;
    const float* bias = bias0 ? (bias0 + (long long)z * sBiasZ) : nullptr;
#pragma unroll
    for (int mi = 0; mi < 8; mi++) {
#pragma unroll
      for (int ni = 0; ni < 4; ni++) {
        const int rr = row0 + mi * 16;
        const int cc = col0 + ni * 16;
        const float bb = bias ? bias[cc] : 0.0f;
#pragma unroll
        for (int j = 0; j < 4; j++) {
          float v = (acc[mi][ni][j] + bb) * scale;
          long long off = (long long)z * sCz + (long long)(rr + j) * ldc + cc;
          if (OUT == 1)
            ((float*)C0v)[off] = v;
          else
            ((__bf16*)C0v)[off] = (__bf16)v;
        }
      }
    }
  }
}

// ---------------------------------------------------------------- softmax (causal, in-place on S bf16)
__global__ __launch_bounds__(256) void softmax_rows(__bf16* __restrict__ S) {
  const int row = blockIdx.x;  // 0..16383 = b*2048 + i
  const int i = row & 2047;
  __bf16* s = S + (long long)row * 2048;
  const int Lpad = (i + 256) & ~255;  // round_up(i+1, 256): PV reads this far
  const int t = threadIdx.x;
  const int j0 = t * 8;
  const int wid = t >> 6, lane = t & 63;
  const bool active = j0 < Lpad;

  float v[8];
  float mymax = -3.0e38f;
  if (active) {
    bf16x8 x = *(const bf16x8*)(s + j0);
#pragma unroll
    for (int e = 0; e < 8; e++) {
      float f = (float)x[e];
      v[e] = ((j0 + e) <= i) ? f : -3.0e38f;
      mymax = fmaxf(mymax, v[e]);
    }
  }
  float mw = mymax;
#pragma unroll
  for (int o = 32; o >= 1; o >>= 1) mw = fmaxf(mw, __shfl_xor(mw, o));
  __shared__ float redm[4];
  __shared__ float reds[4];
  if (lane == 0) redm[wid] = mw;
  __syncthreads();
  const float m = fmaxf(fmaxf(redm[0], redm[1]), fmaxf(redm[2], redm[3]));

  float e8[8];
  float mysum = 0.0f;
  if (active) {
#pragma unroll
    for (int e = 0; e < 8; e++) {
      float ev = ((j0 + e) <= i) ? __expf(v[e] - m) : 0.0f;
      e8[e] = ev;
      mysum += ev;
    }
  } else {
#pragma unroll
    for (int e = 0; e < 8; e++) e8[e] = 0.0f;
  }
  float sw = mysum;
#pragma unroll
  for (int o = 32; o >= 1; o >>= 1) sw += __shfl_xor(sw, o);
  if (lane == 0) reds[wid] = sw;
  __syncthreads();
  const float l = reds[0] + reds[1] + reds[2] + reds[3];
  const float rl = 1.0f / l;
  if (active) {
    bf16x8 o;
#pragma unroll
    for (int e = 0; e < 8; e++) o[e] = (__bf16)(e8[e] * rl);
    *(bf16x8*)(s + j0) = o;
  }
}

// ---------------------------------------------------------------- launch
extern "C" void kernel_launch(void* const* d_in, const int* in_sizes, int n_in,
                              void* d_out, int out_size, void* d_ws, size_t ws_size,
                              hipStream_t stream) {
  const float* y  = (const float*)d_in[0];
  const float* Wq = (const float*)d_in[1];
  const float* bq = (const float*)d_in[2];
  const float* Wk = (const float*)d_in[3];
  const float* bk = (const float*)d_in[4];
  const float* Wv = (const float*)d_in[5];
  const float* bv = (const float*)d_in[6];
  const float* Wo = (const float*)d_in[7];
  const float* bo = (const float*)d_in[8];

  char* ws = (char*)d_ws;
  __bf16* Xb   = (__bf16*)(ws + 0);            // 16384x1024 bf16 X   (32 MiB) [ctx after PV]
  __bf16* Wt   = (__bf16*)(ws + 33554432);     // 4 x [1024][1024] bf16 W^T (8 MiB)
  float*  bqkv = (float*)(ws + 41943040);      // 3x1024 fp32
  __bf16* Qb   = (__bf16*)(ws + 41955328);     // 8x2048x1024 Q       (32 MiB)
  __bf16* Kb   = (__bf16*)(ws + 75509760);     // 8x2048x1024 K       (32 MiB)
  __bf16* Vt   = (__bf16*)(ws + 109064192);    // 8 x [1024][2048] V^T (32 MiB)
  __bf16* Sb   = (__bf16*)(ws + 142618624);    // 8x2048x2048 S/P (ends at 209,727,488)
  __bf16* ctx  = (__bf16*)(ws + 0);            // PV output reuses Xb region

  if (ws_size < 209727488u) return;

  convert_bf16_k<<<2048, 256, 0, stream>>>(y, Xb, 2097152);
  pack_bias_k<<<12, 256, 0, stream>>>(bq, bk, bv, bqkv);
  transpose_w_k<<<dim3(32, 32, 4), dim3(32, 8), 0, stream>>>(Wq, Wk, Wv, Wo, Wt);

  // Fused QKV projection: single launch, z-split (z0->Qb scaled, z1->Kb,
  // z2->Vt via LDS transpose). A-stripe swizzle: XCD q keeps its 4 MiB
  // A-stripe L2-resident across all (z,bc); A fetched ~once from HBM.
  gemm8<2, 1><<<dim3(64, 4, 3), 512, 0, stream>>>(
      Xb, 1024, 0LL, Wt, 1024, 1048576LL,
      Qb, 1024, 16777216LL, bqkv, 1024, 0.03125f, 16, 0, Vt);

  // S = Q @ K^T per batch: packed lower-triangle launch (36 tiles x 8 batches)
  gemm8<0, 2><<<dim3(36, 1, 8), 512, 0, stream>>>(
      Qb, 1024, 2097152LL, Kb, 1024, 2097152LL,
      Sb, 2048, 4194304LL, nullptr, 0, 1.0f, 16, 0, nullptr);

  // causal softmax in place (zero-pads to 256-block edge)
  softmax_rows<<<16384, 256, 0, stream>>>(Sb);

  // ctx = P @ V : kt = 4*(br+1) causal truncation; batch-local swizzle
  // (Vt slice 4 MiB = L2-resident per XCD); ctx into Xb region
  gemm8<0, 3><<<dim3(8, 4, 8), 512, 0, stream>>>(
      Sb, 2048, 4194304LL, Vt, 2048, 2097152LL,
      ctx, 1024, 2097152LL, nullptr, 0, 1.0f, 4, 4, nullptr);

  // out = ctx @ Wo + bo (fp32 epilogue to d_out), A-stripe swizzle
  gemm8<1, 1><<<dim3(64, 4, 1), 512, 0, stream>>>(
      ctx, 1024, 0LL, Wt + 3 * 1048576, 1024, 0LL,
      d_out, 1024, 0LL, bo, 0, 1.0f, 16, 0, nullptr);
}

// Round 5
// 314.608 us; speedup vs baseline: 1.0628x; 1.0080x over previous
//
#include <hip/hip_runtime.h>

typedef __attribute__((ext_vector_type(8))) __bf16 bf16x8;
typedef __attribute__((ext_vector_type(4))) float f32x4;
typedef __attribute__((ext_vector_type(4))) float f4;
typedef __attribute__((ext_vector_type(4))) unsigned short ushort4_t;

__device__ inline void gload16(const void* g, void* l) {
  __builtin_amdgcn_global_load_lds(
      (const __attribute__((address_space(1))) unsigned int*)g,
      (__attribute__((address_space(3))) unsigned int*)l, 16, 0, 0);
}

// ---------------------------------------------------------------- converts
__global__ void convert_bf16_k(const float* __restrict__ in, __bf16* __restrict__ out, int n8) {
  int i = blockIdx.x * blockDim.x + threadIdx.x;
  int stride = gridDim.x * blockDim.x;
  for (; i < n8; i += stride) {
    f4 a = ((const f4*)in)[2 * (long long)i];
    f4 b = ((const f4*)in)[2 * (long long)i + 1];
    bf16x8 o;
#pragma unroll
    for (int e = 0; e < 4; e++) { o[e] = (__bf16)a[e]; o[e + 4] = (__bf16)b[e]; }
    ((bf16x8*)out)[i] = o;
  }
}

__global__ void pack_bias_k(const float* __restrict__ bq, const float* __restrict__ bk,
                            const float* __restrict__ bv, float* __restrict__ out) {
  int i = blockIdx.x * 256 + threadIdx.x;
  if (i >= 3072) return;
  const float* src = (i < 1024) ? bq : (i < 2048) ? bk : bv;
  out[i] = src[i & 1023];
}

// W[k][n] fp32 -> Wt[n][k] bf16, 4 weights via z
__global__ void transpose_w_k(const float* __restrict__ W0, const float* __restrict__ W1,
                              const float* __restrict__ W2, const float* __restrict__ W3,
                              __bf16* __restrict__ out) {
  int z = blockIdx.z;
  const float* W = (z == 0) ? W0 : (z == 1) ? W1 : (z == 2) ? W2 : W3;
  __bf16* O = out + (long long)z * 1048576;
  __shared__ float tile[32][33];
  int tx = threadIdx.x, ty = threadIdx.y;
  int n0 = blockIdx.x * 32, k0 = blockIdx.y * 32;
#pragma unroll
  for (int i = 0; i < 4; i++)
    tile[ty + i * 8][tx] = W[(long long)(k0 + ty + i * 8) * 1024 + n0 + tx];
  __syncthreads();
#pragma unroll
  for (int i = 0; i < 4; i++)
    O[(long long)(n0 + ty + i * 8) * 1024 + k0 + tx] = (__bf16)tile[tx][ty + i * 8];
}

// ---------------------------------------------------------------- GEMM: 256x256 tile, BK=64, 8-phase
// C[z] = A[z] (M x K row-major) @ Bt[z]^T (Bt = N x K row-major) + bias.
// 8 waves (2M x 4N), per-wave 128x64 output, acc[8][4] f32x4.
// LDS 160 KiB: A TRIPLE-buffered (3 x 32 KiB) + B double-buffered (2 x 32 KiB),
// XOR-swizzled (row&7)<<4. A(kk+2) issued during tile kk; B(kk+2)
// overwrites-behind. ENDPB waits vmcnt(8).
// LAST k-tile is PEELED: no staging, no barriers (its buffers were drained at
// the prior ENDPB; in-flight clamped-dup loads target the other A-buf (kt%3)
// and other B-parity (kt&1), so no collision). Each quadrant's C-stores issue
// right after its MFMAQ -> store latency overlaps remaining MFMA work.
// OUT: 0 = bf16 C, 1 = f32 C,
//      2 = fused QKV z-routing: z<2 -> scalar bf16 C (ldc 1024, z*sCz; z==0
//          scaled); z==2 -> V LDS-transposed, coalesced into vt_out[b][d][t].
// SWZ: 0 = generic bijective XCD swizzle (nwg%8==0)
//      1 = A-stripe: XCD q owns br in [8q,8q+8), br fastest, then bc, then z
//          (z SLOWEST: concurrent window = A-stripe 4MiB + ONE 1MiB B panel).
//      2 = packed causal triangle: XCD q = batch q, tri index -> (br,bc), bc<=br
//      3 = batch-local: XCD q = batch q (PV: Vt slice 4MiB = L2-resident)

#define LOADA(BASE, MIB)                                                       \
  _Pragma("unroll") for (int mi = 0; mi < 4; mi++)                             \
      _Pragma("unroll") for (int kh = 0; kh < 2; kh++) {                       \
    int row = ((MIB) + mi) * 16 + ln15;                                        \
    int pb = (row * 128 + (kh * 32 + kq * 8) * 2) ^ ((row & 7) << 4);          \
    a[mi][kh] = *(const bf16x8*)((BASE) + pb);                                 \
  }

#define LOADB(BASE, NIB)                                                       \
  _Pragma("unroll") for (int ni = 0; ni < 2; ni++)                             \
      _Pragma("unroll") for (int kh = 0; kh < 2; kh++) {                       \
    int row = brow0 + ((NIB) + ni) * 16 + ln15;                                \
    int pb = (row * 128 + (kh * 32 + kq * 8) * 2) ^ ((row & 7) << 4);          \
    b[(NIB) + ni][kh] = *(const bf16x8*)((BASE) + pb);                         \
  }

#define MFMAQ(MI0, NI0)                                                        \
  _Pragma("unroll") for (int mi = 0; mi < 4; mi++)                             \
      _Pragma("unroll") for (int ni = 0; ni < 2; ni++)                         \
          _Pragma("unroll") for (int kh = 0; kh < 2; kh++)                     \
              acc[(MI0) + mi][(NI0) + ni] =                                    \
      __builtin_amdgcn_mfma_f32_16x16x32_bf16(a[mi][kh], b[(NI0) + ni][kh],    \
                                              acc[(MI0) + mi][(NI0) + ni], 0, 0, 0);

// store one C-quadrant (skipped for the V z-route, which goes through LDS)
#define STOREQ(MI0, NI0)                                                       \
  if (OUT != 2 || z < 2) {                                                     \
    _Pragma("unroll") for (int mi = 0; mi < 4; mi++)                           \
        _Pragma("unroll") for (int ni = 0; ni < 2; ni++) {                     \
      const int rr = row0 + ((MI0) + mi) * 16;                                 \
      const int cc = col0 + ((NI0) + ni) * 16;                                 \
      const float bb = bias ? bias[cc] : 0.0f;                                 \
      _Pragma("unroll") for (int j = 0; j < 4; j++) {                          \
        float vv = (acc[(MI0) + mi][(NI0) + ni][j] + bb) * scale;              \
        long long off = (long long)z * sCz + (long long)(rr + j) * ldc + cc;   \
        if (OUT == 1) ((float*)C0v)[off] = vv;                                 \
        else ((__bf16*)C0v)[off] = (__bf16)vv;                                 \
      }                                                                        \
    }                                                                          \
  }

#define FENCE asm volatile("" ::: "memory")

#define BARW                                           \
  FENCE;                                               \
  __builtin_amdgcn_s_barrier();                        \
  FENCE;                                               \
  __builtin_amdgcn_s_setprio(1);

#define ENDP                                           \
  __builtin_amdgcn_s_setprio(0);                       \
  FENCE;                                               \
  __builtin_amdgcn_s_barrier();                        \
  FENCE;

#define ENDPB                                          \
  __builtin_amdgcn_s_setprio(0);                       \
  asm volatile("s_waitcnt vmcnt(8)" ::: "memory");     \
  __builtin_amdgcn_s_barrier();                        \
  FENCE;

template <int OUT, int SWZ>
__global__ __launch_bounds__(512, 2) void gemm8(
    const __bf16* __restrict__ A0, int lda, long long sAz,
    const __bf16* __restrict__ B0, int ldb, long long sBz,
    void* __restrict__ C0v, int ldc, long long sCz,
    const float* __restrict__ bias0, int sBiasZ,
    float scale_z0, int k_tiles_base, int k_tiles_per_br,
    __bf16* __restrict__ vt_out) {
  int br, bc, z;
  {
    const int lin = (blockIdx.z * gridDim.y + blockIdx.y) * gridDim.x + blockIdx.x;
    if (SWZ == 1) {
      // A-stripe: XCD q -> br in [8q,8q+8), br fastest; then bc; then z.
      const int q = lin & 7, c = lin >> 3;
      br = q * 8 + (c & 7);
      const int rest = c >> 3;
      const int nby = gridDim.y;
      bc = rest % nby;
      z = rest / nby;
    } else if (SWZ == 2) {
      // packed lower triangle, one batch per XCD; c in [0,36) -> (br,bc) bc<=br
      const int q = lin & 7, c = lin >> 3;
      z = q;
      int b0 = (int)((sqrtf((float)(8 * c + 1)) - 1.0f) * 0.5f);
      int c0 = c - ((b0 * (b0 + 1)) >> 1);
      if (c0 < 0) { b0--; c0 = c - ((b0 * (b0 + 1)) >> 1); }
      if (c0 > b0) { b0++; c0 = c - ((b0 * (b0 + 1)) >> 1); }
      br = b0;
      bc = c0;
    } else if (SWZ == 3) {
      // batch-local: XCD q = batch q; c -> (br fast, bc)
      const int q = lin & 7, c = lin >> 3;
      z = q;
      br = c & 7;
      bc = c >> 3;
    } else {
      const int nbx = gridDim.x, nby = gridDim.y;
      const int nwg = nbx * nby * gridDim.z;
      const int cpx = nwg >> 3;
      const int swz = (lin & 7) * cpx + (lin >> 3);
      br = swz % nbx;
      const int tmp = swz / nbx;
      bc = tmp % nby;
      z = tmp / nby;
    }
  }
  const int kt = k_tiles_base + k_tiles_per_br * br;  // >= 2

  // 160 KiB LDS: A bufs at 0,16384,32768 (elems); B bufs at 49152,65536
  __shared__ __align__(16) __bf16 lds[81920];

  const int t = threadIdx.x, w = t >> 6, lane = t & 63;
  const int wm = w >> 2, wn = w & 3;
  const int ln15 = lane & 15, kq = lane >> 4;
  const int bh = wn >> 1, brow0 = (wn & 1) * 64;

  const __bf16* A = A0 + (long long)z * sAz + (long long)br * 256 * lda;
  const __bf16* B = B0 + (long long)z * sBz + (long long)bc * 256 * ldb;

  // pre-swizzled staging source coords (physical->logical, involution)
  int r0s[2], c0s[2];
#pragma unroll
  for (int i = 0; i < 2; i++) {
    int o = i * 8192 + t * 16;
    int lo = o ^ (((o >> 7) & 7) << 4);
    r0s[i] = lo >> 7;
    c0s[i] = (lo & 127) >> 1;
  }
  // hoisted per-thread source pointers (k-tile adds kc*64 only)
  const __bf16 *sA0[2], *sA1[2], *sB0[2], *sB1[2];
#pragma unroll
  for (int i = 0; i < 2; i++) {
    sA0[i] = A + (long long)r0s[i] * lda + c0s[i];
    sA1[i] = A + (long long)(r0s[i] + 128) * lda + c0s[i];
    sB0[i] = B + (long long)r0s[i] * ldb + c0s[i];
    sB1[i] = B + (long long)(r0s[i] + 128) * ldb + c0s[i];
  }

  auto stg = [&](const __bf16* const* src, __bf16* lbase, int g) {
    int kc = g < kt ? g : kt - 1;  // clamped dup keeps per-iter issue count = 8
#pragma unroll
    for (int i = 0; i < 2; i++)
      gload16(src[i] + kc * 64, lbase + i * 4096 + w * 512);
  };

  f32x4 acc[8][4] = {};
  bf16x8 a[4][2], b[4][2];

  // epilogue coords (used by peeled-tile quadrant stores)
  const int row0 = br * 256 + wm * 128 + kq * 4;
  const int col0 = bc * 256 + wn * 64 + ln15;
  const float scale = (z == 0) ? scale_z0 : 1.0f;
  const float* bias = bias0 ? (bias0 + (long long)z * sBiasZ) : nullptr;

  // prologue: A(0),B(0),A(1),B(1); wait oldest 8 -> A(0),B(0) resident
  stg(sA0, lds, 0);
  stg(sA1, lds + 8192, 0);
  stg(sB0, lds + 49152, 0);
  stg(sB1, lds + 49152 + 8192, 0);
  stg(sA0, lds + 16384, 1);
  stg(sA1, lds + 16384 + 8192, 1);
  stg(sB0, lds + 65536, 1);
  stg(sB1, lds + 65536 + 8192, 1);
  asm volatile("s_waitcnt vmcnt(8)" ::: "memory");
  __builtin_amdgcn_s_barrier();
  FENCE;

  int ap = 0;   // A buffer index of tile kk (mod 3)
  int ad = 2;   // A buffer index of tile kk+2 (= (ap+2)%3)
  for (int kk = 0; kk < kt - 1; kk++) {
    __bf16* Ab = lds + ap * 16384;
    __bf16* Bb = lds + 49152 + (kk & 1) * 16384;
    __bf16* Ad = lds + ad * 16384;  // dest for A(kk+2)
    __bf16* Bd = Bb;                // B(kk+2) overwrites-behind
    const char* Aw = (const char*)(Ab + wm * 8192);
    const char* Bw = (const char*)(Bb + bh * 8192);
    // phase 1
    LOADA(Aw, 0) LOADB(Bw, 0)
    stg(sA0, Ad, kk + 2);
    BARW MFMAQ(0, 0) ENDP
    // phase 2
    LOADB(Bw, 2)
    stg(sA1, Ad + 8192, kk + 2);
    BARW MFMAQ(0, 2) ENDP
    // phase 3 (B ds_reads all done by end of phase 2 -> safe to overwrite)
    LOADA(Aw, 4)
    stg(sB0, Bd, kk + 2);
    BARW MFMAQ(4, 2) ENDP
    // phase 4
    stg(sB1, Bd + 8192, kk + 2);
    BARW MFMAQ(4, 0) ENDPB
    ap = (ap == 2) ? 0 : ap + 1;
    ad = (ad == 2) ? 0 : ad + 1;
  }

  // ---- peeled last tile: no staging, no barriers; stores overlap MFMA ----
  {
    __bf16* Ab = lds + ap * 16384;
    __bf16* Bb = lds + 49152 + ((kt - 1) & 1) * 16384;
    const char* Aw = (const char*)(Ab + wm * 8192);
    const char* Bw = (const char*)(Bb + bh * 8192);
    LOADA(Aw, 0) LOADB(Bw, 0) LOADB(Bw, 2)
    __builtin_amdgcn_s_setprio(1);
    MFMAQ(0, 0)
    STOREQ(0, 0)
    MFMAQ(0, 2)
    STOREQ(0, 2)
    LOADA(Aw, 4)
    MFMAQ(4, 2)
    STOREQ(4, 2)
    MFMAQ(4, 0)
    __builtin_amdgcn_s_setprio(0);
    STOREQ(4, 0)
  }

  // ---- V epilogue (QKV z==2): LDS-transpose then coalesced stores ----
  if (OUT == 2 && z == 2) {
    // __syncthreads waits vmcnt(0)+lgkmcnt(0): drains in-flight clamped dup
    // prefetches and all waves' ds_reads before LDS reuse.
    __syncthreads();
    char* lb = (char*)lds;
    const int dl0 = wn * 64 + ln15;
    const int tl0 = wm * 128 + kq * 4;
#pragma unroll
    for (int mi = 0; mi < 8; mi++) {
#pragma unroll
      for (int ni = 0; ni < 4; ni++) {
        const int d = dl0 + ni * 16;
        const int tl = tl0 + mi * 16;
        const float bb = bias0[2048 + bc * 256 + d];
        ushort4_t p;
#pragma unroll
        for (int j = 0; j < 4; j++) {
          union { __bf16 h; unsigned short u; } cv;
          cv.h = (__bf16)(acc[mi][ni][j] + bb);
          p[j] = cv.u;
        }
        int byte = d * 512 + tl * 2;
        byte ^= (d & 7) << 4;
        *(ushort4_t*)(lb + byte) = p;
      }
    }
    __syncthreads();
    const int bz = br >> 3;
    __bf16* vbase = vt_out + (long long)bz * 2097152 +
                    (long long)(bc * 256) * 2048 + (br & 7) * 256;
#pragma unroll
    for (int it = 0; it < 16; it++) {
      int idx = it * 512 + t;
      int d = idx >> 5, tc = idx & 31;
      int byte = d * 512 + tc * 16;
      byte ^= (d & 7) << 4;
      bf16x8 vv = *(const bf16x8*)(lb + byte);
      *(bf16x8*)(vbase + (long long)d * 2048 + tc * 8) = vv;
    }
  }
}

// ---------------------------------------------------------------- softmax (causal, in-place on S bf16)
__global__ __launch_bounds__(256) void softmax_rows(__bf16* __restrict__ S) {
  const int row = blockIdx.x;  // 0..16383 = b*2048 + i
  const int i = row & 2047;
  __bf16* s = S + (long long)row * 2048;
  const int Lpad = (i + 256) & ~255;  // round_up(i+1, 256): PV reads this far
  const int t = threadIdx.x;
  const int j0 = t * 8;
  const int wid = t >> 6, lane = t & 63;
  const bool active = j0 < Lpad;

  float v[8];
  float mymax = -3.0e38f;
  if (active) {
    bf16x8 x = *(const bf16x8*)(s + j0);
#pragma unroll
    for (int e = 0; e < 8; e++) {
      float f = (float)x[e];
      v[e] = ((j0 + e) <= i) ? f : -3.0e38f;
      mymax = fmaxf(mymax, v[e]);
    }
  }
  float mw = mymax;
#pragma unroll
  for (int o = 32; o >= 1; o >>= 1) mw = fmaxf(mw, __shfl_xor(mw, o));
  __shared__ float redm[4];
  __shared__ float reds[4];
  if (lane == 0) redm[wid] = mw;
  __syncthreads();
  const float m = fmaxf(fmaxf(redm[0], redm[1]), fmaxf(redm[2], redm[3]));

  float e8[8];
  float mysum = 0.0f;
  if (active) {
#pragma unroll
    for (int e = 0; e < 8; e++) {
      float ev = ((j0 + e) <= i) ? __expf(v[e] - m) : 0.0f;
      e8[e] = ev;
      mysum += ev;
    }
  } else {
#pragma unroll
    for (int e = 0; e < 8; e++) e8[e] = 0.0f;
  }
  float sw = mysum;
#pragma unroll
  for (int o = 32; o >= 1; o >>= 1) sw += __shfl_xor(sw, o);
  if (lane == 0) reds[wid] = sw;
  __syncthreads();
  const float l = reds[0] + reds[1] + reds[2] + reds[3];
  const float rl = 1.0f / l;
  if (active) {
    bf16x8 o;
#pragma unroll
    for (int e = 0; e < 8; e++) o[e] = (__bf16)(e8[e] * rl);
    *(bf16x8*)(s + j0) = o;
  }
}

// ---------------------------------------------------------------- launch
extern "C" void kernel_launch(void* const* d_in, const int* in_sizes, int n_in,
                              void* d_out, int out_size, void* d_ws, size_t ws_size,
                              hipStream_t stream) {
  const float* y  = (const float*)d_in[0];
  const float* Wq = (const float*)d_in[1];
  const float* bq = (const float*)d_in[2];
  const float* Wk = (const float*)d_in[3];
  const float* bk = (const float*)d_in[4];
  const float* Wv = (const float*)d_in[5];
  const float* bv = (const float*)d_in[6];
  const float* Wo = (const float*)d_in[7];
  const float* bo = (const float*)d_in[8];

  char* ws = (char*)d_ws;
  __bf16* Xb   = (__bf16*)(ws + 0);            // 16384x1024 bf16 X   (32 MiB) [ctx after PV]
  __bf16* Wt   = (__bf16*)(ws + 33554432);     // 4 x [1024][1024] bf16 W^T (8 MiB)
  float*  bqkv = (float*)(ws + 41943040);      // 3x1024 fp32
  __bf16* Qb   = (__bf16*)(ws + 41955328);     // 8x2048x1024 Q       (32 MiB)
  __bf16* Kb   = (__bf16*)(ws + 75509760);     // 8x2048x1024 K       (32 MiB)
  __bf16* Vt   = (__bf16*)(ws + 109064192);    // 8 x [1024][2048] V^T (32 MiB)
  __bf16* Sb   = (__bf16*)(ws + 142618624);    // 8x2048x2048 S/P (ends at 209,727,488)
  __bf16* ctx  = (__bf16*)(ws + 0);            // PV output reuses Xb region

  if (ws_size < 209727488u) return;

  convert_bf16_k<<<2048, 256, 0, stream>>>(y, Xb, 2097152);
  pack_bias_k<<<12, 256, 0, stream>>>(bq, bk, bv, bqkv);
  transpose_w_k<<<dim3(32, 32, 4), dim3(32, 8), 0, stream>>>(Wq, Wk, Wv, Wo, Wt);

  // Fused QKV projection: single launch, z-split (z0->Qb scaled, z1->Kb,
  // z2->Vt via LDS transpose). A-stripe swizzle, z slowest: per-XCD window =
  // A-stripe 4 MiB + one 1 MiB weight panel (L2-fit; weights fetched ~once).
  gemm8<2, 1><<<dim3(64, 4, 3), 512, 0, stream>>>(
      Xb, 1024, 0LL, Wt, 1024, 1048576LL,
      Qb, 1024, 16777216LL, bqkv, 1024, 0.03125f, 16, 0, Vt);

  // S = Q @ K^T per batch: packed lower-triangle launch (36 tiles x 8 batches)
  gemm8<0, 2><<<dim3(36, 1, 8), 512, 0, stream>>>(
      Qb, 1024, 2097152LL, Kb, 1024, 2097152LL,
      Sb, 2048, 4194304LL, nullptr, 0, 1.0f, 16, 0, nullptr);

  // causal softmax in place (zero-pads to 256-block edge)
  softmax_rows<<<16384, 256, 0, stream>>>(Sb);

  // ctx = P @ V : kt = 4*(br+1) causal truncation; batch-local swizzle
  // (Vt slice 4 MiB = L2-resident per XCD); ctx into Xb region
  gemm8<0, 3><<<dim3(8, 4, 8), 512, 0, stream>>>(
      Sb, 2048, 4194304LL, Vt, 2048, 2097152LL,
      ctx, 1024, 2097152LL, nullptr, 0, 1.0f, 4, 4, nullptr);

  // out = ctx @ Wo + bo (fp32 epilogue to d_out), A-stripe swizzle
  gemm8<1, 1><<<dim3(64, 4, 1), 512, 0, stream>>>(
      ctx, 1024, 0LL, Wt + 3 * 1048576, 1024, 0LL,
      d_out, 1024, 0LL, bo, 0, 1.0f, 16, 0, nullptr);
}